// Round 5
// baseline (674.865 us; speedup 1.0000x reference)
//
#include <hip/hip_runtime.h>
#include <float.h>

#define DIM      512
#define NCLS     21
#define MARGIN_V 5.0f
#define NWAVES   8                  // waves per block; wave w owns d-slice [w*64, w*64+64)
#define DSLICE   (DIM / NWAVES)     // 64
#define RPL      4                  // rows per lane; acc[4][21] = 84 VGPRs
#define ROWS_PB  (64 * RPL)         // 256 rows per block; grid 256 = 1 block/CU
#define CHUNK    16                 // d-floats per chunk (4 float4 = one 64B line per row)
#define NCHUNK   (DSLICE / CHUNK)   // 4
#define CLDSF    (NCLS * DIM)       // 10752 floats: centers table (43008 B)
#define SST      85                 // odd scalar combine stride -> conflict-free b32
#define SCRF     (4 * 64 * SST)     // 21760 floats combine scratch
#define LDSF     SCRF               // max(centers 10752, scratch 21760) = 21760 (87040 B)

// Kernel 1: halfc2[c] = 0.5 * ||centers[c]||^2  -> d_ws
__global__ __launch_bounds__(64)
void center_norm_kernel(const float* __restrict__ centers,
                        float* __restrict__ halfc2) {
    const int c = blockIdx.x;
    const int t = threadIdx.x;
    float s = 0.f;
#pragma unroll
    for (int i = 0; i < DIM / 64; ++i) {
        float v = centers[c * DIM + i * 64 + t];
        s = fmaf(v, v, s);
    }
#pragma unroll
    for (int off = 32; off > 0; off >>= 1)
        s += __shfl_down(s, off, 64);
    if (t == 0) halfc2[c] = 0.5f * s;
}

// Kernel 2: 8 waves/block; wave w handles d-slice [w*64,w*64+64) of 256 rows,
// lane t owns rows {t, t+64, t+128, t+192}. Features go global->VGPR directly
// (each lane reads its own full 64B lines: 4 consecutive dwordx4 per row-chunk,
// L1-resident -> exact-fetch; round 4's 4x over-fetch + tile bank conflicts
// both came from the LDS feature round-trip, now deleted). LDS holds only the
// centers table (uniform ds_read_b128 broadcasts, conflict-free, amortized
// over 4 rows/lane) and the end-of-kernel combine scratch.
__global__ __launch_bounds__(512, 1)
void tcl_main_kernel(const float* __restrict__ feat,
                     const float* __restrict__ centers,
                     const int* __restrict__ labels,
                     const float* __restrict__ halfc2,
                     float* __restrict__ out) {
    __shared__ float lds[LDSF];

    const int tid  = threadIdx.x;
    const int w    = __builtin_amdgcn_readfirstlane(tid >> 6);  // uniform wave id
    const int t    = tid & 63;
    const int row0 = blockIdx.x * ROWS_PB;

    int labv[RPL];
    if (w == 0) {
#pragma unroll
        for (int r = 0; r < RPL; ++r) labv[r] = labels[row0 + t + r * 64];
    }

    float acc[RPL][NCLS];
#pragma unroll
    for (int r = 0; r < RPL; ++r)
#pragma unroll
        for (int c = 0; c < NCLS; ++c) acc[r][c] = 0.f;

    const float4* f4p = reinterpret_cast<const float4*>(feat);
    size_t rb[RPL];
#pragma unroll
    for (int r = 0; r < RPL; ++r)
        rb[r] = (size_t)(row0 + t + r * 64) * (DIM / 4) + (size_t)w * (DSLICE / 4);

    // prologue: chunk-0 feature loads (fly while centers stage)
    float4 fv[RPL][4];
#pragma unroll
    for (int r = 0; r < RPL; ++r)
#pragma unroll
        for (int j = 0; j < 4; ++j)
            fv[r][j] = f4p[rb[r] + j];
    __builtin_amdgcn_sched_barrier(0);

    // stage centers table into LDS (block-cooperative, float4)
    float4* l4 = reinterpret_cast<float4*>(lds);
    {
        const float4* c4 = reinterpret_cast<const float4*>(centers);
#pragma unroll
        for (int i = 0; i < (CLDSF / 4 + 511) / 512; ++i) {
            int idx = i * 512 + tid;
            if (idx < CLDSF / 4) l4[idx] = c4[idx];
        }
    }
    __syncthreads();

#pragma unroll 1
    for (int kk = 0; kk < NCHUNK; ++kk) {
        const int dq = w * (DSLICE / 4) + kk * 4;   // f4 index of chunk base
#pragma unroll
        for (int q = 0; q < 4; ++q) {
            // 3 groups of 7 classes bound center-VGPR liveness (28 regs)
#pragma unroll
            for (int ch = 0; ch < 3; ++ch) {
                float4 cv[7];
#pragma unroll
                for (int k = 0; k < 7; ++k)
                    cv[k] = l4[(ch * 7 + k) * (DIM / 4) + dq + q];
#pragma unroll
                for (int k = 0; k < 7; ++k) {
                    const int c = ch * 7 + k;
#pragma unroll
                    for (int r = 0; r < RPL; ++r) {
                        acc[r][c] = fmaf(fv[r][q].x, cv[k].x,
                                     fmaf(fv[r][q].y, cv[k].y,
                                      fmaf(fv[r][q].z, cv[k].z,
                                       fmaf(fv[r][q].w, cv[k].w, acc[r][c]))));
                    }
                }
            }
        }
        // reload fv with next chunk (issued here, consumed next iteration;
        // second wave on the SIMD covers the boundary latency)
        if (kk + 1 < NCHUNK) {
#pragma unroll
            for (int r = 0; r < RPL; ++r)
#pragma unroll
                for (int j = 0; j < 4; ++j)
                    fv[r][j] = f4p[rb[r] + (kk + 1) * 4 + j];
        }
        __builtin_amdgcn_sched_barrier(0);
    }

    // ---- cross-wave combine: 8 -> 4 -> 2 -> 1, scalar b32, odd stride 85 ----
    float* scratch = lds;   // centers no longer needed
    __syncthreads();
    if (w >= 4) {
        float* p = &scratch[((w - 4) * 64 + t) * SST];
#pragma unroll
        for (int r = 0; r < RPL; ++r)
#pragma unroll
            for (int c = 0; c < NCLS; ++c) p[r * NCLS + c] = acc[r][c];
    }
    __syncthreads();
    if (w < 4) {
        const float* p = &scratch[(w * 64 + t) * SST];
#pragma unroll
        for (int r = 0; r < RPL; ++r)
#pragma unroll
            for (int c = 0; c < NCLS; ++c) acc[r][c] += p[r * NCLS + c];
    }
    __syncthreads();
    if (w == 2 || w == 3) {
        float* p = &scratch[((w - 2) * 64 + t) * SST];
#pragma unroll
        for (int r = 0; r < RPL; ++r)
#pragma unroll
            for (int c = 0; c < NCLS; ++c) p[r * NCLS + c] = acc[r][c];
    }
    __syncthreads();
    if (w < 2) {
        const float* p = &scratch[(w * 64 + t) * SST];
#pragma unroll
        for (int r = 0; r < RPL; ++r)
#pragma unroll
            for (int c = 0; c < NCLS; ++c) acc[r][c] += p[r * NCLS + c];
    }
    __syncthreads();
    if (w == 1) {
        float* p = &scratch[t * SST];
#pragma unroll
        for (int r = 0; r < RPL; ++r)
#pragma unroll
            for (int c = 0; c < NCLS; ++c) p[r * NCLS + c] = acc[r][c];
    }
    __syncthreads();
    if (w == 0) {
        const float* p = &scratch[t * SST];
        float vsum = 0.f;
#pragma unroll
        for (int r = 0; r < RPL; ++r) {
            const int lab = labv[r];
            float pos = 0.f, neg = FLT_MAX;
#pragma unroll
            for (int c = 0; c < NCLS; ++c) {
                float e = halfc2[c] - (acc[r][c] + p[r * NCLS + c]);
                pos = (c == lab) ? e : pos;
                neg = (c == lab) ? neg : fminf(neg, e);
            }
            vsum += fmaxf(pos + MARGIN_V - neg, 0.f);
        }
#pragma unroll
        for (int off = 32; off > 0; off >>= 1)
            vsum += __shfl_down(vsum, off, 64);
        if (t == 0) atomicAdd(out, vsum * (1.0f / 65536.f));
    }
}

extern "C" void kernel_launch(void* const* d_in, const int* in_sizes, int n_in,
                              void* d_out, int out_size, void* d_ws, size_t ws_size,
                              hipStream_t stream) {
    const float* feat    = (const float*)d_in[0];   // (65536, 512) fp32
    const float* centers = (const float*)d_in[1];   // (21, 512) fp32
    const int*   labels  = (const int*)d_in[2];     // (65536,) int
    float* out    = (float*)d_out;                  // scalar loss
    float* halfc2 = (float*)d_ws;                   // 21 floats scratch

    hipMemsetAsync(d_out, 0, (size_t)out_size * sizeof(float), stream);
    center_norm_kernel<<<NCLS, 64, 0, stream>>>(centers, halfc2);

    const int nblocks = 65536 / ROWS_PB;            // 256 blocks x 8 waves = 1 block/CU
    tcl_main_kernel<<<nblocks, 512, 0, stream>>>(feat, centers, labels, halfc2, out);
}

// Round 6
// 210.746 us; speedup vs baseline: 3.2023x; 3.2023x over previous
//
#include <hip/hip_runtime.h>
#include <float.h>

#define DIM      512
#define NCLS     21
#define MARGIN_V 5.0f
#define NWAVES   8                 // waves per block; wave w owns d-slice [w*64, w*64+64)
#define DSLICE   (DIM / NWAVES)    // 64 floats = 16 float4 per lane, held in VGPRs
#define ROWS_PB  64                // one row per lane, shared by all 8 waves
#define SST      (NCLS + 1)        // 22: combine stride, 2-way conflicts = free
#define LDSF     (4 * 64 * SST)    // 5632 floats = 22528 B combine scratch only

// Kernel 1: halfc2[c] = 0.5 * ||centers[c]||^2  -> d_ws
__global__ __launch_bounds__(64)
void center_norm_kernel(const float* __restrict__ centers,
                        float* __restrict__ halfc2) {
    const int c = blockIdx.x;
    const int t = threadIdx.x;
    float s = 0.f;
#pragma unroll
    for (int i = 0; i < DIM / 64; ++i) {
        float v = centers[c * DIM + i * 64 + t];
        s = fmaf(v, v, s);
    }
#pragma unroll
    for (int off = 32; off > 0; off >>= 1)
        s += __shfl_down(s, off, 64);
    if (t == 0) halfc2[c] = 0.5f * s;
}

// Kernel 2: 8 waves/block share 64 rows; wave w owns d-slice [w*64, w*64+64).
// Lane t holds row (row0+t)'s 64-float slice entirely in VGPRs (16 float4,
// loaded once, reused across all 21 classes -> features read exactly once,
// no LDS, no DS-pipe traffic). Center values are wave-uniform -> compiler
// emits s_load_dwordx16 + SGPR-operand v_fmac (free operand slot); fully
// unrolled 21x64 straight-line body gives the scalar unit ~2700 cycles of
// slack to prefetch 84 scalar loads. ~90 VGPRs: no spills at the 128 cap.
__global__ __launch_bounds__(512, 1)
void tcl_main_kernel(const float* __restrict__ feat,
                     const float* __restrict__ centers,
                     const int* __restrict__ labels,
                     const float* __restrict__ halfc2,
                     float* __restrict__ out) {
    __shared__ float scratch[LDSF];

    const int tid  = threadIdx.x;
    const int w    = __builtin_amdgcn_readfirstlane(tid >> 6);  // uniform wave id
    const int t    = tid & 63;
    const int row0 = blockIdx.x * ROWS_PB;

    int lab = 0;
    if (w == 0) lab = labels[row0 + t];

    float acc[NCLS];
#pragma unroll
    for (int c = 0; c < NCLS; ++c) acc[c] = 0.f;

    // Load this lane's full 64-float d-slice: 16 consecutive dwordx4 = 4 full
    // 64B lines, contiguous per lane -> exact fetch, fully consumed.
    const float4* f4p = reinterpret_cast<const float4*>(feat);
    const size_t  rb  = (size_t)(row0 + t) * (DIM / 4) + (size_t)w * (DSLICE / 4);
    float4 fv[16];
#pragma unroll
    for (int j = 0; j < 16; ++j) fv[j] = f4p[rb + j];

    // Straight-line: 21 classes x 64 FMAs; center operand wave-uniform scalar.
    const int dbase = w * DSLICE;
#pragma unroll
    for (int c = 0; c < NCLS; ++c) {
        const float* __restrict__ cp = &centers[c * DIM + dbase];
        float a = acc[c];
#pragma unroll
        for (int j = 0; j < 16; ++j) {
            a = fmaf(fv[j].x, cp[4 * j + 0],
                 fmaf(fv[j].y, cp[4 * j + 1],
                  fmaf(fv[j].z, cp[4 * j + 2],
                   fmaf(fv[j].w, cp[4 * j + 3], a))));
        }
        acc[c] = a;
    }

    // ---- cross-wave combine: 8 -> 4 -> 2 -> 1, scalar b32, stride 22 ----
    __syncthreads();
    if (w >= 4) {
        float* p = &scratch[((w - 4) * 64 + t) * SST];
#pragma unroll
        for (int c = 0; c < NCLS; ++c) p[c] = acc[c];
    }
    __syncthreads();
    if (w < 4) {
        const float* p = &scratch[(w * 64 + t) * SST];
#pragma unroll
        for (int c = 0; c < NCLS; ++c) acc[c] += p[c];
    }
    __syncthreads();
    if (w == 2 || w == 3) {
        float* p = &scratch[((w - 2) * 64 + t) * SST];
#pragma unroll
        for (int c = 0; c < NCLS; ++c) p[c] = acc[c];
    }
    __syncthreads();
    if (w < 2) {
        const float* p = &scratch[(w * 64 + t) * SST];
#pragma unroll
        for (int c = 0; c < NCLS; ++c) acc[c] += p[c];
    }
    __syncthreads();
    if (w == 1) {
        float* p = &scratch[t * SST];
#pragma unroll
        for (int c = 0; c < NCLS; ++c) p[c] = acc[c];
    }
    __syncthreads();
    if (w == 0) {
        const float* p = &scratch[t * SST];
        float pos = 0.f, neg = FLT_MAX;
#pragma unroll
        for (int c = 0; c < NCLS; ++c) {
            float e = halfc2[c] - (acc[c] + p[c]);
            pos = (c == lab) ? e : pos;
            neg = (c == lab) ? neg : fminf(neg, e);
        }
        float v = fmaxf(pos + MARGIN_V - neg, 0.f);
#pragma unroll
        for (int off = 32; off > 0; off >>= 1)
            v += __shfl_down(v, off, 64);
        if (t == 0) atomicAdd(out, v * (1.0f / 65536.f));
    }
}

extern "C" void kernel_launch(void* const* d_in, const int* in_sizes, int n_in,
                              void* d_out, int out_size, void* d_ws, size_t ws_size,
                              hipStream_t stream) {
    const float* feat    = (const float*)d_in[0];   // (65536, 512) fp32
    const float* centers = (const float*)d_in[1];   // (21, 512) fp32
    const int*   labels  = (const int*)d_in[2];     // (65536,) int
    float* out    = (float*)d_out;                  // scalar loss
    float* halfc2 = (float*)d_ws;                   // 21 floats scratch

    hipMemsetAsync(d_out, 0, (size_t)out_size * sizeof(float), stream);
    center_norm_kernel<<<NCLS, 64, 0, stream>>>(centers, halfc2);

    const int nblocks = 65536 / ROWS_PB;            // 1024 blocks x 8 waves
    tcl_main_kernel<<<nblocks, 512, 0, stream>>>(feat, centers, labels, halfc2, out);
}